// Round 13
// baseline (212.089 us; speedup 1.0000x reference)
//
#include <hip/hip_runtime.h>
#include <hip/hip_bf16.h>
#include <cstddef>

#define Bb 32
#define Tt 1000
#define Ii 256
#define Hh 512
#define CHK 96      // 3 stripes x 32 t
#define NPH 11      // chunks 0..10; chunk 10 = 40-t tail

typedef __attribute__((ext_vector_type(8))) short short8;
typedef __attribute__((ext_vector_type(4))) float f32x4;

__device__ __forceinline__ unsigned short f2bfu(float f) {
  return __builtin_bit_cast(unsigned short, __float2bfloat16(f));
}

// ---- scan NP pairs (2 timesteps per LDS u32), serial LIF recurrence ----
template <int NP>
__device__ __forceinline__ void scan_run(const unsigned int* cw,
                                         float* zp, float* tp,
                                         float& v, bool& zb, float& tr) {
  const float dm = 0.9512294245007140f, om = 0.0487705754992860f;
  unsigned int ring[8];
#pragma unroll
  for (int j = 0; j < 8; ++j)
    if (j < NP) ring[j] = cw[j];

  auto step = [&](unsigned int bits16, int t) {
    const float cur = __builtin_bit_cast(float, bits16 << 16);  // bf16 -> f32
    const float omc = om * cur;
    const float w = fmaf(v, dm, omc);     // speculative no-reset path
    v = zb ? omc : w;                     // multiplicative reset on old z
    zb = v > 1.0f;                        // spike((v-THR)/THR), THR=1
    tr = fmaf(tr, dm, zb ? om : 0.0f);    // exp_convolve
    __builtin_nontemporal_store(zb ? 1.0f : 0.0f, zp + (size_t)t * Hh);
    __builtin_nontemporal_store(tr, tp + (size_t)t * Hh);
  };

  int g = 0;
  for (; g + 8 <= NP; g += 8) {
#pragma unroll
    for (int j = 0; j < 8; ++j) {
      const unsigned int c2 = ring[j];
      if (g + j + 8 < NP) ring[j] = cw[g + j + 8];
      step(c2 & 0xffffu, 2 * (g + j));
      step(c2 >> 16, 2 * (g + j) + 1);
    }
  }
#pragma unroll
  for (int j = 0; j < 8; ++j) {
    if (j < (NP & 7)) {
      const unsigned int c2 = ring[j];
      step(c2 & 0xffffu, 2 * (g + j));
      step(c2 >> 16, 2 * (g + j) + 1);
    }
  }
}

// Fused GEMM + LIF scan, rotating scanner.
// 256 blocks (8 ht x 32 b) = 1/CU, 4 waves. Phase c: wave (c&3) scans chunk c
// (state via LDS); other 3 waves (rank r) MFMA stripe r of chunk c+1 from
// global-x-in-registers (no A LDS tile). Only __syncthreads barriers.
__global__ __launch_bounds__(256, 1) void lif_fused3(const float* __restrict__ X,
                                                     const float* __restrict__ Wf,
                                                     float* __restrict__ Z,
                                                     float* __restrict__ TR) {
  __shared__ short cc[2][64 * 98];   // currents [h][96+2 pad] bf16, dbuf (24.5 KB)
  __shared__ float vst[64], trst[64], zst[64];  // scan-state handoff

  const int tid = threadIdx.x;
  const int ht = blockIdx.x;         // 0..7
  const int b = blockIdx.y;          // 0..31
  const int lane = tid & 63;
  const int wid = tid >> 6;          // 0..3
  const int fl = lane & 15, fj = lane >> 4;

  // ---- W fragments in registers, every wave (128 VGPR; 1 wave/SIMD so free) ----
  short8 wfrag[8][4];
#pragma unroll
  for (int s = 0; s < 8; ++s)
#pragma unroll
    for (int nj = 0; nj < 4; ++nj) {
      const float* wp = Wf + (size_t)(ht * 64 + nj * 16 + fl) * Ii + s * 32 + fj * 8;
      f32x4 w0 = *(const f32x4*)wp, w1 = *(const f32x4*)(wp + 4);
      short8 vv;
#pragma unroll
      for (int e = 0; e < 4; ++e) {
        vv[e] = (short)f2bfu(w0[e]);
        vv[4 + e] = (short)f2bfu(w1[e]);
      }
      wfrag[s][nj] = vv;
    }

  const float* xb = X + (size_t)b * Tt * Ii;

  // compute stripe r (32 t) of chunk c: A f32 global->regs in fragment layout,
  // convert, MFMA vs wfrag, write bf16 currents into ccb.
  auto gemm_chunk = [&](int c, int r, short* ccb) {
    const int ts = r * 32;
    f32x4 a[2][8][2];                 // 128 VGPR, all loads issued up front
#pragma unroll
    for (int mt = 0; mt < 2; ++mt) {
      int row = c * CHK + ts + mt * 16 + fl;
      row = row < Tt ? row : (Tt - 1);          // tail clamp (results unread)
      const float* bp = xb + (size_t)row * Ii + fj * 8;
#pragma unroll
      for (int s = 0; s < 8; ++s) {
        a[mt][s][0] = *(const f32x4*)(bp + s * 32);
        a[mt][s][1] = *(const f32x4*)(bp + s * 32 + 4);
      }
    }
    f32x4 acc[2][4];
#pragma unroll
    for (int mt = 0; mt < 2; ++mt)
#pragma unroll
      for (int nj = 0; nj < 4; ++nj) acc[mt][nj] = (f32x4)0.0f;

#pragma unroll
    for (int s = 0; s < 8; ++s) {
      short8 af[2];
#pragma unroll
      for (int mt = 0; mt < 2; ++mt)
#pragma unroll
        for (int e = 0; e < 4; ++e) {
          af[mt][e] = (short)f2bfu(a[mt][s][0][e]);
          af[mt][4 + e] = (short)f2bfu(a[mt][s][1][e]);
        }
#pragma unroll
      for (int mt = 0; mt < 2; ++mt)
#pragma unroll
        for (int nj = 0; nj < 4; ++nj)
          acc[mt][nj] = __builtin_amdgcn_mfma_f32_16x16x32_bf16(
              af[mt], wfrag[s][nj], acc[mt][nj], 0, 0, 0);
    }
    // C/D: col=lane&15 -> h = nj*16+fl; row = fj*4+q -> t = ts+mt*16+fj*4+q
#pragma unroll
    for (int mt = 0; mt < 2; ++mt)
#pragma unroll
      for (int nj = 0; nj < 4; ++nj) {
        const int h = nj * 16 + fl;
        const int rr = ts + mt * 16 + fj * 4;
#pragma unroll
        for (int qp = 0; qp < 2; ++qp) {
          const unsigned int pk =
              ((unsigned)f2bfu(acc[mt][nj][2 * qp + 1]) << 16) |
              f2bfu(acc[mt][nj][2 * qp]);
          *(unsigned int*)(ccb + h * 98 + rr + 2 * qp) = pk;
        }
      }
  };

  // ---- prologue: chunk 0 -> cc[0] by waves 1..3 ----
  if (wid) gemm_chunk(0, wid - 1, &cc[0][0]);
  __syncthreads();

  for (int c = 0; c < NPH; ++c) {
    const int s = c & 3;
    if (wid == s) {
      float v, tr;
      bool zb;
      if (c == 0) {
        v = 0.0f; tr = 0.0f; zb = false;
      } else {
        v = vst[lane]; tr = trst[lane]; zb = (zst[lane] != 0.0f);
      }
      const unsigned int* cw = (const unsigned int*)(&cc[c & 1][0] + lane * 98);
      float* zp = Z + ((size_t)b * Tt + c * CHK) * Hh + ht * 64 + lane;
      float* tp = TR + ((size_t)b * Tt + c * CHK) * Hh + ht * 64 + lane;
      if (c < NPH - 1)
        scan_run<48>(cw, zp, tp, v, zb, tr);
      else
        scan_run<20>(cw, zp, tp, v, zb, tr);   // tail: 40 t
      vst[lane] = v; trst[lane] = tr; zst[lane] = zb ? 1.0f : 0.0f;
    } else if (c + 1 < NPH) {
      const int r = (wid - s - 1) & 3;         // 0..2 among non-scanners
      gemm_chunk(c + 1, r, &cc[(c + 1) & 1][0]);
    }
    __syncthreads();
  }
}

extern "C" void kernel_launch(void* const* d_in, const int* in_sizes, int n_in,
                              void* d_out, int out_size, void* d_ws, size_t ws_size,
                              hipStream_t stream) {
  const float* x = (const float*)d_in[0];   // [B,T,I] f32
  const float* W = (const float*)d_in[1];   // [H,I]  f32
  float* out = (float*)d_out;
  float* zout = out;                                  // [B,T,H]
  float* trout = out + (size_t)Bb * Tt * Hh;          // [B,T,H]

  hipLaunchKernelGGL(lif_fused3, dim3(8, 32), dim3(256), 0, stream,
                     x, W, zout, trout);
}